// Round 7
// baseline (49.228 us; speedup 1.0000x reference)
//
#include <hip/hip_runtime.h>

typedef __attribute__((ext_vector_type(8))) short    bf16x8;
typedef __attribute__((ext_vector_type(4))) float    f32x4;
typedef __attribute__((ext_vector_type(4))) float    float4_t;
typedef __attribute__((ext_vector_type(4))) unsigned u32x4;
typedef __attribute__((ext_vector_type(2))) unsigned u32x2;

constexpr int NSAMP    = 32768;
constexpr int INSZ     = 255;
constexpr int DIM      = 256;      // IN_SIZE + bias
constexpr int NSPLIT   = 1023;
constexpr int NCOL     = 1024;     // 1023 split cols + W as col 1023
constexpr int BM       = 32;       // samples per block
constexpr int NTHREADS = 256;      // 4 waves
constexpr int NMT      = BM / 16;  // M-tiles per wave = 2
constexpr int NPASS    = 64 / 4;   // col-tiles per wave = 16

// LDS layout (80 KiB/block -> 2 blocks/CU):
//  [0, 16384)     : phase 1 = x tile bf16 [32][256], byte ^= (row&7)<<4
//                   phase 2 = Wz f32[2048] at [0,8K) ; part f32[32][64] at [8K,16K)
//  [16384, 81920) : XA bf16 [row 0..31][pos 0..1023], pos = split_id+1, pos 0 = x.Wx
//                   within-row byte ^= ((row>>2)&3)<<5   (disjoint 32B chunks per
//                   row-group -> conflict-free MFMA-result stores)
constexpr int XA_OFF    = 16384;
constexpr int PART_OFF  = 8192;
constexpr int PSTRIDE   = 64;                           // floats
constexpr int LDS_BYTES = XA_OFF + BM * 2048;           // 81920
constexpr size_t WS_NEED = (size_t)NCOL * DIM * 2;      // 512 KiB bf16 fragment buffer

extern __shared__ char smem[];

__device__ __forceinline__ short f2bf(float f) {
  unsigned x = __builtin_bit_cast(unsigned, f);
  x += 0x7fffu + ((x >> 16) & 1u);            // RNE
  return (short)(x >> 16);
}
__device__ __forceinline__ float bfraw(unsigned hw16) {
  return __builtin_bit_cast(float, hw16 << 16);
}
__device__ __forceinline__ unsigned cvt_pk(float lo, float hi) {
  unsigned r;
  asm("v_cvt_pk_bf16_f32 %0, %1, %2" : "=v"(r) : "v"(lo), "v"(hi));
  return r;
}
__device__ __forceinline__ float clamp01(float v) {
  return fminf(fmaxf(v, 0.f), 1.f);
}

// ---------------- prep: A (f32) + W row -> bf16 MFMA-fragment layout in d_ws ------------
// u32x4 index = ct*512 + ks*64 + lane
// holds A[col = ct*16 + (lane&15)][k = ks*32 + (lane>>4)*8 .. +8)  (col 1023 -> W[0:256))
__global__ void prep_frag(const float* __restrict__ A, const float* __restrict__ W,
                          u32x4* __restrict__ wsf)
{
  int t    = blockIdx.x * 512 + threadIdx.x;      // 0..32767
  int lane = t & 63;
  int ks   = (t >> 6) & 7;
  int ct   = t >> 9;
  int col  = ct * 16 + (lane & 15);
  int k0   = ks * 32 + ((lane >> 4) << 3);
  const float* src = (col < NSPLIT) ? (A + col * DIM + k0) : (W + k0);
  float4_t a0 = *(const float4_t*)src;
  float4_t a1 = *(const float4_t*)(src + 4);
  u32x4 p;
  p[0] = cvt_pk(a0[0], a0[1]);
  p[1] = cvt_pk(a0[2], a0[3]);
  p[2] = cvt_pk(a1[0], a1[1]);
  p[3] = cvt_pk(a1[2], a1[3]);
  wsf[t] = p;
}

// ---------------- B-fragment load (one col-tile, all 8 k-steps) ----------------
template<bool USE_WS>
__device__ __forceinline__ void load_bfr(int ct, bf16x8* dst, int lane,
                                         const u32x4* __restrict__ wsf,
                                         const float* __restrict__ A,
                                         const float* __restrict__ W)
{
  if constexpr (USE_WS) {
    const u32x4* fp = wsf + ct * 512 + lane;
#pragma unroll
    for (int ks = 0; ks < 8; ++ks)
      dst[ks] = __builtin_bit_cast(bf16x8, fp[ks * 64]);
  } else {
    int col = ct * 16 + (lane & 15);
    int k0  = (lane >> 4) << 3;
    const float* ap = (col < NSPLIT) ? (A + col * DIM) : W;
#pragma unroll
    for (int ks = 0; ks < 8; ++ks) {
      float4_t a0 = *(const float4_t*)(ap + ks * 32 + k0);
      float4_t a1 = *(const float4_t*)(ap + ks * 32 + k0 + 4);
      u32x4 p;
      p[0] = cvt_pk(a0[0], a0[1]);
      p[1] = cvt_pk(a0[2], a0[3]);
      p[2] = cvt_pk(a1[0], a1[1]);
      p[3] = cvt_pk(a1[2], a1[3]);
      dst[ks] = __builtin_bit_cast(bf16x8, p);
    }
  }
}

// ---------------- per-sample tree walk (round-1-verified math) ----------------
// lane-parallel over nodes; returns this lane's partial of sum_i clip(q_i)*Wz_i
__device__ __forceinline__ float walk(const char* __restrict__ xar, int swz,
                                      const float* __restrict__ wz, int lane)
{
  float acc = 0.f;
  float q   = 1.0f;
  // levels 1..6: one node per lane (i = lane), parent q via shuffle
#pragma unroll
  for (int l = 1; l <= 6; ++l) {
    float qp = __shfl(q, lane >> 1, 64);
    int  pos = (1 << (l - 1)) + (lane >> 1);           // split_id + 1
    unsigned hw = *(const unsigned short*)(xar + (((pos << 1)) ^ swz));
    float xa = bfraw(hw);
    float e  = (lane & 1) ? -xa : xa;
    q = fminf(qp, e);
    if (lane < (1 << l))
      acc += clamp01(q) * wz[(1 << l) + lane];
  }
  // level 7: i = 2*lane + {0,1}; parent split id 63+lane -> pos 64+lane
  unsigned h7 = *(const unsigned short*)(xar + ((((64 + lane) << 1)) ^ swz));
  float xa7 = bfraw(h7);
  float q7a = fminf(q, xa7), q7b = fminf(q, -xa7);
  acc += clamp01(q7a) * wz[128 + 2 * lane]
       + clamp01(q7b) * wz[128 + 2 * lane + 1];
  // level 8: i = 4*lane + c; xa pos 128+2*lane+{0,1}
  unsigned u8 = *(const unsigned*)(xar + (((256 + 4 * lane)) ^ swz));
  float x8a = bfraw(u8 & 0xffffu), x8b = bfraw(u8 >> 16);
  float q8[4];
  q8[0] = fminf(q7a, x8a);  q8[1] = fminf(q7a, -x8a);
  q8[2] = fminf(q7b, x8b);  q8[3] = fminf(q7b, -x8b);
  {
    float4_t w8 = *(const float4_t*)(wz + 256 + 4 * lane);
    acc += clamp01(q8[0]) * w8[0] + clamp01(q8[1]) * w8[1]
         + clamp01(q8[2]) * w8[2] + clamp01(q8[3]) * w8[3];
  }
  // level 9: i = 8*lane + c; xa pos 256+4*lane+{0..3}
  u32x2 u9 = *(const u32x2*)(xar + (((512 + 8 * lane)) ^ swz));
  float x9[4] = { bfraw(u9[0] & 0xffffu), bfraw(u9[0] >> 16),
                  bfraw(u9[1] & 0xffffu), bfraw(u9[1] >> 16) };
  float q9[8];
#pragma unroll
  for (int c = 0; c < 8; ++c)
    q9[c] = fminf(q8[c >> 1], (c & 1) ? -x9[c >> 1] : x9[c >> 1]);
  {
    float4_t w9a = *(const float4_t*)(wz + 512 + 8 * lane);
    float4_t w9b = *(const float4_t*)(wz + 512 + 8 * lane + 4);
#pragma unroll
    for (int c = 0; c < 4; ++c) acc += clamp01(q9[c]) * w9a[c];
#pragma unroll
    for (int c = 0; c < 4; ++c) acc += clamp01(q9[4 + c]) * w9b[c];
  }
  // level 10: i = 16*lane + c; xa pos 512+8*lane+{0..7}
  u32x2 uA = *(const u32x2*)(xar + (((1024 + 16 * lane)) ^ swz));
  u32x2 uB = *(const u32x2*)(xar + (((1024 + 16 * lane + 8)) ^ swz));
  float xA[8] = { bfraw(uA[0] & 0xffffu), bfraw(uA[0] >> 16),
                  bfraw(uA[1] & 0xffffu), bfraw(uA[1] >> 16),
                  bfraw(uB[0] & 0xffffu), bfraw(uB[0] >> 16),
                  bfraw(uB[1] & 0xffffu), bfraw(uB[1] >> 16) };
  {
    float4_t wA0 = *(const float4_t*)(wz + 1024 + 16 * lane);
    float4_t wA1 = *(const float4_t*)(wz + 1024 + 16 * lane + 4);
    float4_t wA2 = *(const float4_t*)(wz + 1024 + 16 * lane + 8);
    float4_t wA3 = *(const float4_t*)(wz + 1024 + 16 * lane + 12);
#pragma unroll
    for (int c = 0; c < 16; ++c) {
      float qv = fminf(q9[c >> 1], (c & 1) ? -xA[c >> 1] : xA[c >> 1]);
      float wv = (c < 4) ? wA0[c] : (c < 8) ? wA1[c - 4] : (c < 12) ? wA2[c - 8] : wA3[c - 12];
      acc += clamp01(qv) * wv;
    }
  }
  return acc;
}

// ---------------- fused main kernel ----------------
// 80 KiB LDS -> 2 blocks/CU (independent blocks overlap each other's phases).
// 8 waves/CU = 2 waves/EU; pin register budget to that occupancy (256 VGPR).
// Phase order matches the verified round-5 topology exactly: Wz is staged AFTER
// the phase-1 barrier (staging it before phase 1 correlated with NaN in r2/r6).
template<bool USE_WS>
__global__ __launch_bounds__(NTHREADS) __attribute__((amdgpu_waves_per_eu(2, 2)))
void lt_main(const float* __restrict__ X, const float* __restrict__ A,
             const float* __restrict__ W, const float* __restrict__ Bv,
             const u32x4* __restrict__ wsf, float* __restrict__ Out)
{
  const int tid  = threadIdx.x;
  const int lane = tid & 63;
  const int wave = tid >> 6;
  const int m0   = blockIdx.x * BM;

  // ---- issue pass-0 B fragments early (L2 latency overlaps X staging) ----
  bf16x8 b0[8], b1[8];
  load_bfr<USE_WS>(wave, b0, lane, wsf, A, W);

  // ---- stage x tile: contiguous 32*255 f32 region, float4 loads ----
  {
    const float4_t* Xt = (const float4_t*)(X + (size_t)m0 * INSZ);
#pragma unroll
    for (int i = 0; i < 8; ++i) {
      int idx = tid + i * NTHREADS;
      if (idx < 2040) {                      // 32*255/4
        float4_t v = Xt[idx];
#pragma unroll
        for (int e = 0; e < 4; ++e) {
          int g   = idx * 4 + e;
          int row = g / 255;
          int col = g - row * 255;
          *(short*)(smem + (((row << 9) + (col << 1)) ^ ((row & 7) << 4))) = f2bf(v[e]);
        }
      }
    }
    if (tid < BM)                            // bias column (=1.0)
      *(short*)(smem + (((tid << 9) + (255 << 1)) ^ ((tid & 7) << 4))) = (short)0x3f80;
  }
  __syncthreads();

  // ---- preload x fragments: 2 M-tiles x 8 K-steps (32 VGPR) ----
  bf16x8 xf[NMT][8];
#pragma unroll
  for (int mt = 0; mt < NMT; ++mt) {
    int row = mt * 16 + (lane & 15);
#pragma unroll
    for (int ks = 0; ks < 8; ++ks) {
      int kk = ks * 32 + ((lane >> 4) << 3);
      xf[mt][ks] = *(const bf16x8*)(smem + (((row << 9) + (kk << 1)) ^ ((row & 7) << 4)));
    }
  }
  // no barrier needed: phase 1 below never touches the x-tile region

  // ---- phase 1: 16 passes; wave owns col-tile ct = p*4 + wave ----
#pragma unroll
  for (int p = 0; p < NPASS; ++p) {
    bf16x8* cur = (p & 1) ? b1 : b0;
    bf16x8* nxt = (p & 1) ? b0 : b1;
    if (p < NPASS - 1)
      load_bfr<USE_WS>((p + 1) * 4 + wave, nxt, lane, wsf, A, W);   // prefetch next

    f32x4 acc[NMT];
#pragma unroll
    for (int mt = 0; mt < NMT; ++mt) acc[mt] = f32x4{0.f, 0.f, 0.f, 0.f};
#pragma unroll
    for (int ks = 0; ks < 8; ++ks) {
#pragma unroll
      for (int mt = 0; mt < NMT; ++mt)
        acc[mt] = __builtin_amdgcn_mfma_f32_16x16x32_bf16(xf[mt][ks], cur[ks], acc[mt], 0, 0, 0);
    }

    // write XA: row-major [sample][pos], pos = col+1, W col -> pos 0
    // swz = ((row>>2)&3)<<5: the 4 row-groups of a store hit disjoint 32B chunks
    int col = (p * 4 + wave) * 16 + (lane & 15);
    int pos = (col < NSPLIT) ? (col + 1) : 0;
#pragma unroll
    for (int mt = 0; mt < NMT; ++mt) {
#pragma unroll
      for (int j = 0; j < 4; ++j) {
        int row = mt * 16 + ((lane >> 4) << 2) + j;
        int byt = XA_OFF + (row << 11) + (((pos << 1)) ^ (((row >> 2) & 3) << 5));
        *(short*)(smem + byt) = f2bf(acc[mt][j]);
      }
    }
  }
  __syncthreads();

  // ---- stage Wz (shifted by +1 for alignment) into dead x-tile region ----
  for (int i = tid; i < 2048; i += NTHREADS) {
    float w = (i > 0) ? W[DIM + i - 1] : 0.f;
    *(float*)(smem + (i << 2)) = w;
  }
  __syncthreads();

  // ---- phase 2: 8 samples per wave, 2 at a time for ILP ----
  const float* wz   = (const float*)smem;
  float*       part = (float*)(smem + PART_OFF);

#pragma unroll
  for (int t = 0; t < 4; ++t) {
    int rA = wave * 8 + 2 * t;
    int rB = rA + 1;
    const char* xarA = smem + XA_OFF + (rA << 11);
    const char* xarB = smem + XA_OFF + (rB << 11);
    const int swzA = ((rA >> 2) & 3) << 5;
    const int swzB = ((rB >> 2) & 3) << 5;
    float accA = walk(xarA, swzA, wz, lane);
    float accB = walk(xarB, swzB, wz, lane);
    part[rA * PSTRIDE + lane] = accA;
    part[rB * PSTRIDE + lane] = accB;
  }
  __syncthreads();

  // ---- final reduction: 8 lanes per sample (256 threads -> 32 samples) ----
  {
    int r = tid >> 3, j = tid & 7;
    const float* pr = part + r * PSTRIDE + j * 8;
    float4_t s0 = *(const float4_t*)pr;
    float4_t s1 = *(const float4_t*)(pr + 4);
    float sum = ((s0[0] + s0[1]) + (s0[2] + s0[3]))
              + ((s1[0] + s1[1]) + (s1[2] + s1[3]));
    sum += __shfl_xor(sum, 1, 64);
    sum += __shfl_xor(sum, 2, 64);
    sum += __shfl_xor(sum, 4, 64);
    if (j == 0) {
      const char* xar = smem + XA_OFF + (r << 11);
      int swz = ((r >> 2) & 3) << 5;
      float xw = bfraw(*(const unsigned short*)(xar + (0 ^ swz)));   // x.Wx from MFMA col
      float bias = Bv[0] + W[DIM];           // b + root weight (z_root = 1)
      Out[m0 + r] = 1.f / (1.f + __expf(-(sum + xw + bias)));
    }
  }
}

extern "C" void kernel_launch(void* const* d_in, const int* in_sizes, int n_in,
                              void* d_out, int out_size, void* d_ws, size_t ws_size,
                              hipStream_t stream) {
  (void)in_sizes; (void)n_in; (void)out_size;
  const float* X  = (const float*)d_in[0];
  const float* A  = (const float*)d_in[1];
  const float* W  = (const float*)d_in[2];
  const float* Bv = (const float*)d_in[3];
  float* Out = (float*)d_out;

  const bool use_ws = (d_ws != nullptr) && (ws_size >= WS_NEED);
  if (use_ws) {
    prep_frag<<<64, 512, 0, stream>>>(A, W, (u32x4*)d_ws);
    hipFuncSetAttribute(reinterpret_cast<const void*>(lt_main<true>),
                        hipFuncAttributeMaxDynamicSharedMemorySize, LDS_BYTES);
    lt_main<true><<<NSAMP / BM, NTHREADS, LDS_BYTES, stream>>>(
        X, A, W, Bv, (const u32x4*)d_ws, Out);
  } else {
    hipFuncSetAttribute(reinterpret_cast<const void*>(lt_main<false>),
                        hipFuncAttributeMaxDynamicSharedMemorySize, LDS_BYTES);
    lt_main<false><<<NSAMP / BM, NTHREADS, LDS_BYTES, stream>>>(
        X, A, W, Bv, nullptr, Out);
  }
}

// Round 8
// 44.008 us; speedup vs baseline: 1.1186x; 1.1186x over previous
//
#include <hip/hip_runtime.h>

typedef __attribute__((ext_vector_type(8))) short    bf16x8;
typedef __attribute__((ext_vector_type(4))) float    f32x4;
typedef __attribute__((ext_vector_type(4))) float    float4_t;
typedef __attribute__((ext_vector_type(4))) unsigned u32x4;
typedef __attribute__((ext_vector_type(2))) unsigned u32x2;

constexpr int NSAMP    = 32768;
constexpr int INSZ     = 255;
constexpr int DIM      = 256;      // IN_SIZE + bias
constexpr int NSPLIT   = 1023;
constexpr int NCOL     = 1024;     // 1023 split cols + W as col 1023
constexpr int BM       = 32;       // samples per block
constexpr int NTHREADS = 256;      // 4 waves
constexpr int NMT      = BM / 16;  // M-tiles per wave = 2
constexpr int NPASS    = 64 / 4;   // col-tiles per wave = 16

// LDS layout (80 KiB/block -> 2 blocks/CU):
//  [0, 16384)     : phase 1 = x tile bf16 [32][256], byte ^= (row&7)<<4
//                   phase 2 = part f32[32][64] at [8K,16K)
//  [16384, 81920) : XA bf16 [row 0..31][pos 0..1023], pos = split_id+1, pos 0 = x.Wx
//                   within-row byte ^= ((row>>2)&3)<<5   (disjoint 32B chunks per
//                   row-group -> conflict-free MFMA-result stores)
constexpr int XA_OFF    = 16384;
constexpr int PART_OFF  = 8192;
constexpr int PSTRIDE   = 64;                           // floats
constexpr int LDS_BYTES = XA_OFF + BM * 2048;           // 81920
constexpr size_t WS_NEED = (size_t)NCOL * DIM * 2;      // 512 KiB bf16 fragment buffer

extern __shared__ char smem[];

__device__ __forceinline__ short f2bf(float f) {
  unsigned x = __builtin_bit_cast(unsigned, f);
  x += 0x7fffu + ((x >> 16) & 1u);            // RNE
  return (short)(x >> 16);
}
__device__ __forceinline__ float bfraw(unsigned hw16) {
  return __builtin_bit_cast(float, hw16 << 16);
}
__device__ __forceinline__ unsigned cvt_pk(float lo, float hi) {
  unsigned r;
  asm("v_cvt_pk_bf16_f32 %0, %1, %2" : "=v"(r) : "v"(lo), "v"(hi));
  return r;
}
__device__ __forceinline__ float clamp01(float v) {
  return fminf(fmaxf(v, 0.f), 1.f);
}

// ---------------- prep: A (f32) + W row -> bf16 MFMA-fragment layout in d_ws ------------
// u32x4 index = ct*512 + ks*64 + lane
// holds A[col = ct*16 + (lane&15)][k = ks*32 + (lane>>4)*8 .. +8)  (col 1023 -> W[0:256))
__global__ void prep_frag(const float* __restrict__ A, const float* __restrict__ W,
                          u32x4* __restrict__ wsf)
{
  int t    = blockIdx.x * 512 + threadIdx.x;      // 0..32767
  int lane = t & 63;
  int ks   = (t >> 6) & 7;
  int ct   = t >> 9;
  int col  = ct * 16 + (lane & 15);
  int k0   = ks * 32 + ((lane >> 4) << 3);
  const float* src = (col < NSPLIT) ? (A + col * DIM + k0) : (W + k0);
  float4_t a0 = *(const float4_t*)src;
  float4_t a1 = *(const float4_t*)(src + 4);
  u32x4 p;
  p[0] = cvt_pk(a0[0], a0[1]);
  p[1] = cvt_pk(a0[2], a0[3]);
  p[2] = cvt_pk(a1[0], a1[1]);
  p[3] = cvt_pk(a1[2], a1[3]);
  wsf[t] = p;
}

// ---------------- B-fragment load (one col-tile, all 8 k-steps) ----------------
template<bool USE_WS>
__device__ __forceinline__ void load_bfr(int ct, bf16x8* dst, int lane,
                                         const u32x4* __restrict__ wsf,
                                         const float* __restrict__ A,
                                         const float* __restrict__ W)
{
  if constexpr (USE_WS) {
    const u32x4* fp = wsf + ct * 512 + lane;
#pragma unroll
    for (int ks = 0; ks < 8; ++ks)
      dst[ks] = __builtin_bit_cast(bf16x8, fp[ks * 64]);
  } else {
    int col = ct * 16 + (lane & 15);
    int k0  = (lane >> 4) << 3;
    const float* ap = (col < NSPLIT) ? (A + col * DIM) : W;
#pragma unroll
    for (int ks = 0; ks < 8; ++ks) {
      float4_t a0 = *(const float4_t*)(ap + ks * 32 + k0);
      float4_t a1 = *(const float4_t*)(ap + ks * 32 + k0 + 4);
      u32x4 p;
      p[0] = cvt_pk(a0[0], a0[1]);
      p[1] = cvt_pk(a0[2], a0[3]);
      p[2] = cvt_pk(a1[0], a1[1]);
      p[3] = cvt_pk(a1[2], a1[3]);
      dst[ks] = __builtin_bit_cast(bf16x8, p);
    }
  }
}

// ---------------- per-sample tree walk (weights in registers) ----------------
// lane-parallel over nodes; returns this lane's partial of sum_i clip(q_i)*Wz_i
__device__ __forceinline__ float walk(const char* __restrict__ xar, int swz, int lane,
                                      const float* __restrict__ wl,   // [6] levels 1..6
                                      float w7a, float w7b,
                                      const float* __restrict__ w8r,  // [4]
                                      const float* __restrict__ w9r,  // [8]
                                      const float* __restrict__ wAr)  // [16]
{
  float acc = 0.f;
  float q   = 1.0f;
  // levels 1..6: one node per lane (i = lane), parent q via shuffle
  // wl[l-1] is 0 for inactive lanes, so the add is unconditional
#pragma unroll
  for (int l = 1; l <= 6; ++l) {
    float qp = __shfl(q, lane >> 1, 64);
    int  pos = (1 << (l - 1)) + (lane >> 1);           // split_id + 1
    unsigned hw = *(const unsigned short*)(xar + (((pos << 1)) ^ swz));
    float xa = bfraw(hw);
    float e  = (lane & 1) ? -xa : xa;
    q = fminf(qp, e);
    acc += clamp01(q) * wl[l - 1];
  }
  // level 7: i = 2*lane + {0,1}; parent split id 63+lane -> pos 64+lane
  unsigned h7 = *(const unsigned short*)(xar + ((((64 + lane) << 1)) ^ swz));
  float xa7 = bfraw(h7);
  float q7a = fminf(q, xa7), q7b = fminf(q, -xa7);
  acc += clamp01(q7a) * w7a + clamp01(q7b) * w7b;
  // level 8: i = 4*lane + c; xa pos 128+2*lane+{0,1}
  unsigned u8 = *(const unsigned*)(xar + (((256 + 4 * lane)) ^ swz));
  float x8a = bfraw(u8 & 0xffffu), x8b = bfraw(u8 >> 16);
  float q8[4];
  q8[0] = fminf(q7a, x8a);  q8[1] = fminf(q7a, -x8a);
  q8[2] = fminf(q7b, x8b);  q8[3] = fminf(q7b, -x8b);
#pragma unroll
  for (int c = 0; c < 4; ++c) acc += clamp01(q8[c]) * w8r[c];
  // level 9: i = 8*lane + c; xa pos 256+4*lane+{0..3}  (8B @ 8B stride: conflict-free)
  u32x2 u9 = *(const u32x2*)(xar + (((512 + 8 * lane)) ^ swz));
  float x9[4] = { bfraw(u9[0] & 0xffffu), bfraw(u9[0] >> 16),
                  bfraw(u9[1] & 0xffffu), bfraw(u9[1] >> 16) };
  float q9[8];
#pragma unroll
  for (int c = 0; c < 8; ++c)
    q9[c] = fminf(q8[c >> 1], (c & 1) ? -x9[c >> 1] : x9[c >> 1]);
#pragma unroll
  for (int c = 0; c < 8; ++c) acc += clamp01(q9[c]) * w9r[c];
  // level 10: i = 16*lane + c; xa pos 512+8*lane+{0..7}
  // single b128 (16B @ 16B stride: contiguous 1KB span, conflict-free)
  u32x4 uAB = *(const u32x4*)(xar + (((1024 + 16 * lane)) ^ swz));
  float xA[8] = { bfraw(uAB[0] & 0xffffu), bfraw(uAB[0] >> 16),
                  bfraw(uAB[1] & 0xffffu), bfraw(uAB[1] >> 16),
                  bfraw(uAB[2] & 0xffffu), bfraw(uAB[2] >> 16),
                  bfraw(uAB[3] & 0xffffu), bfraw(uAB[3] >> 16) };
#pragma unroll
  for (int c = 0; c < 16; ++c) {
    float qv = fminf(q9[c >> 1], (c & 1) ? -xA[c >> 1] : xA[c >> 1]);
    acc += clamp01(qv) * wAr[c];
  }
  return acc;
}

// ---------------- fused main kernel ----------------
// 80 KiB LDS -> 2 blocks/CU (independent blocks overlap each other's phases).
// 8 waves/CU = 2 waves/EU; pin register budget to that occupancy (256 VGPR).
template<bool USE_WS>
__global__ __launch_bounds__(NTHREADS) __attribute__((amdgpu_waves_per_eu(2, 2)))
void lt_main(const float* __restrict__ X, const float* __restrict__ A,
             const float* __restrict__ W, const float* __restrict__ Bv,
             const u32x4* __restrict__ wsf, float* __restrict__ Out)
{
  const int tid  = threadIdx.x;
  const int lane = tid & 63;
  const int wave = tid >> 6;
  const int m0   = blockIdx.x * BM;

  // ---- issue pass-0 B fragments early (L2 latency overlaps X staging) ----
  bf16x8 b0[8], b1[8];
  load_bfr<USE_WS>(wave, b0, lane, wsf, A, W);

  // ---- hoist phase-2 tree weights into registers (t-invariant; latency hides
  //      under phases 0-1; global reads are coalesced + L2-resident, no LDS) ----
  float wl[6], w8r[4], w9r[8], wAr[16];
#pragma unroll
  for (int l = 1; l <= 6; ++l)
    wl[l - 1] = (lane < (1 << l)) ? W[DIM + (1 << l) - 1 + lane] : 0.f;
  float w7a = W[DIM + 127 + 2 * lane];
  float w7b = W[DIM + 128 + 2 * lane];
#pragma unroll
  for (int e = 0; e < 4; ++e)  w8r[e] = W[DIM + 255 + 4 * lane + e];
#pragma unroll
  for (int e = 0; e < 8; ++e)  w9r[e] = W[DIM + 511 + 8 * lane + e];
#pragma unroll
  for (int e = 0; e < 16; ++e) wAr[e] = W[DIM + 1023 + 16 * lane + e];

  // ---- stage x tile: contiguous 32*255 f32 region, float4 loads ----
  {
    const float4_t* Xt = (const float4_t*)(X + (size_t)m0 * INSZ);
#pragma unroll
    for (int i = 0; i < 8; ++i) {
      int idx = tid + i * NTHREADS;
      if (idx < 2040) {                      // 32*255/4
        float4_t v = Xt[idx];
#pragma unroll
        for (int e = 0; e < 4; ++e) {
          int g   = idx * 4 + e;
          int row = g / 255;
          int col = g - row * 255;
          *(short*)(smem + (((row << 9) + (col << 1)) ^ ((row & 7) << 4))) = f2bf(v[e]);
        }
      }
    }
    if (tid < BM)                            // bias column (=1.0)
      *(short*)(smem + (((tid << 9) + (255 << 1)) ^ ((tid & 7) << 4))) = (short)0x3f80;
  }
  __syncthreads();

  // ---- preload x fragments: 2 M-tiles x 8 K-steps (32 VGPR) ----
  bf16x8 xf[NMT][8];
#pragma unroll
  for (int mt = 0; mt < NMT; ++mt) {
    int row = mt * 16 + (lane & 15);
#pragma unroll
    for (int ks = 0; ks < 8; ++ks) {
      int kk = ks * 32 + ((lane >> 4) << 3);
      xf[mt][ks] = *(const bf16x8*)(smem + (((row << 9) + (kk << 1)) ^ ((row & 7) << 4)));
    }
  }
  // no barrier needed: phase 1 below never touches the x-tile region

  // ---- phase 1: 16 passes; wave owns col-tile ct = p*4 + wave ----
#pragma unroll
  for (int p = 0; p < NPASS; ++p) {
    bf16x8* cur = (p & 1) ? b1 : b0;
    bf16x8* nxt = (p & 1) ? b0 : b1;
    if (p < NPASS - 1)
      load_bfr<USE_WS>((p + 1) * 4 + wave, nxt, lane, wsf, A, W);   // prefetch next

    f32x4 acc[NMT];
#pragma unroll
    for (int mt = 0; mt < NMT; ++mt) acc[mt] = f32x4{0.f, 0.f, 0.f, 0.f};
#pragma unroll
    for (int ks = 0; ks < 8; ++ks) {
#pragma unroll
      for (int mt = 0; mt < NMT; ++mt)
        acc[mt] = __builtin_amdgcn_mfma_f32_16x16x32_bf16(xf[mt][ks], cur[ks], acc[mt], 0, 0, 0);
    }

    // write XA: row-major [sample][pos], pos = col+1, W col -> pos 0
    // swz = ((row>>2)&3)<<5: the 4 row-groups of a store hit disjoint 32B chunks
    int col = (p * 4 + wave) * 16 + (lane & 15);
    int pos = (col < NSPLIT) ? (col + 1) : 0;
#pragma unroll
    for (int mt = 0; mt < NMT; ++mt) {
#pragma unroll
      for (int j = 0; j < 4; ++j) {
        int row = mt * 16 + ((lane >> 4) << 2) + j;
        int byt = XA_OFF + (row << 11) + (((pos << 1)) ^ (((row >> 2) & 3) << 5));
        *(short*)(smem + byt) = f2bf(acc[mt][j]);
      }
    }
  }
  __syncthreads();

  // ---- phase 2: 8 samples per wave, 2 at a time for ILP ----
  float* part = (float*)(smem + PART_OFF);

#pragma unroll
  for (int t = 0; t < 4; ++t) {
    int rA = wave * 8 + 2 * t;
    int rB = rA + 1;
    const char* xarA = smem + XA_OFF + (rA << 11);
    const char* xarB = smem + XA_OFF + (rB << 11);
    const int swzA = ((rA >> 2) & 3) << 5;
    const int swzB = ((rB >> 2) & 3) << 5;
    float accA = walk(xarA, swzA, lane, wl, w7a, w7b, w8r, w9r, wAr);
    float accB = walk(xarB, swzB, lane, wl, w7a, w7b, w8r, w9r, wAr);
    part[rA * PSTRIDE + lane] = accA;
    part[rB * PSTRIDE + lane] = accB;
  }
  __syncthreads();

  // ---- final reduction: 8 lanes per sample (256 threads -> 32 samples) ----
  {
    int r = tid >> 3, j = tid & 7;
    const float* pr = part + r * PSTRIDE + j * 8;
    float4_t s0 = *(const float4_t*)pr;
    float4_t s1 = *(const float4_t*)(pr + 4);
    float sum = ((s0[0] + s0[1]) + (s0[2] + s0[3]))
              + ((s1[0] + s1[1]) + (s1[2] + s1[3]));
    sum += __shfl_xor(sum, 1, 64);
    sum += __shfl_xor(sum, 2, 64);
    sum += __shfl_xor(sum, 4, 64);
    if (j == 0) {
      const char* xar = smem + XA_OFF + (r << 11);
      int swz = ((r >> 2) & 3) << 5;
      float xw = bfraw(*(const unsigned short*)(xar + (0 ^ swz)));   // x.Wx from MFMA col
      float bias = Bv[0] + W[DIM];           // b + root weight (z_root = 1)
      Out[m0 + r] = 1.f / (1.f + __expf(-(sum + xw + bias)));
    }
  }
}

extern "C" void kernel_launch(void* const* d_in, const int* in_sizes, int n_in,
                              void* d_out, int out_size, void* d_ws, size_t ws_size,
                              hipStream_t stream) {
  (void)in_sizes; (void)n_in; (void)out_size;
  const float* X  = (const float*)d_in[0];
  const float* A  = (const float*)d_in[1];
  const float* W  = (const float*)d_in[2];
  const float* Bv = (const float*)d_in[3];
  float* Out = (float*)d_out;

  const bool use_ws = (d_ws != nullptr) && (ws_size >= WS_NEED);
  if (use_ws) {
    prep_frag<<<64, 512, 0, stream>>>(A, W, (u32x4*)d_ws);
    hipFuncSetAttribute(reinterpret_cast<const void*>(lt_main<true>),
                        hipFuncAttributeMaxDynamicSharedMemorySize, LDS_BYTES);
    lt_main<true><<<NSAMP / BM, NTHREADS, LDS_BYTES, stream>>>(
        X, A, W, Bv, (const u32x4*)d_ws, Out);
  } else {
    hipFuncSetAttribute(reinterpret_cast<const void*>(lt_main<false>),
                        hipFuncAttributeMaxDynamicSharedMemorySize, LDS_BYTES);
    lt_main<false><<<NSAMP / BM, NTHREADS, LDS_BYTES, stream>>>(
        X, A, W, Bv, nullptr, Out);
  }
}

// Round 10
// 39.393 us; speedup vs baseline: 1.2496x; 1.1171x over previous
//
#include <hip/hip_runtime.h>

typedef __attribute__((ext_vector_type(8))) short    bf16x8;
typedef __attribute__((ext_vector_type(4))) float    f32x4;
typedef __attribute__((ext_vector_type(4))) float    float4_t;
typedef __attribute__((ext_vector_type(4))) unsigned u32x4;

constexpr int NSAMP    = 32768;
constexpr int INSZ     = 255;
constexpr int DIM      = 256;      // IN_SIZE + bias
constexpr int NSPLIT   = 1023;
constexpr int NCOL     = 1024;     // 1023 split cols + W as col 1023
constexpr int BM       = 64;       // samples per block (halves per-sample A-traffic)
constexpr int NTHREADS = 512;      // 8 waves
constexpr int NMT      = 4;        // M-tiles per wave
constexpr int NPASS    = 8;        // col-tile passes per wave (64 tiles / 8 waves)

// LDS (exactly 160 KiB, 1 block/CU):
//  [0, 32768)      : x tile bf16 [64][256], byte ^= (row&7)<<4
//                    (reused as part[8][64] f32 AFTER phase 1 completes)
//  [32768, 163840) : XA_T bf16 [node 0..1023][sample 0..63]
//                    byte = node*128 + ((sample*2) ^ sw(node)),
//                    sw(node) = ((node&15)<<3) | ((node&1)<<2)
//                    -> 2 lanes/bank (free) on MFMA-output stores AND walk reads
constexpr int XA_OFF    = 32768;
constexpr int LDS_BYTES = XA_OFF + NCOL * 128;          // 163840
constexpr size_t WS_NEED = (size_t)NCOL * DIM * 2;      // 512 KiB bf16 fragment buffer

extern __shared__ char smem[];

// NOTE (r2/r6/r9 lesson): converting MFMA ACCUMULATOR outputs with the inline-asm
// v_cvt_pk_bf16_f32 correlates perfectly with NaN output (3/3 fails vs 6/6 passes
// with f2bf). Suspected MFMA->inline-asm hazard on AGPR-resident values. Only use
// cvt_pk on plain load-produced VGPR data (prep_frag); use f2bf on accumulators.
__device__ __forceinline__ short f2bf(float f) {
  unsigned x = __builtin_bit_cast(unsigned, f);
  x += 0x7fffu + ((x >> 16) & 1u);            // RNE
  return (short)(x >> 16);
}
__device__ __forceinline__ float bfraw(unsigned hw16) {
  return __builtin_bit_cast(float, hw16 << 16);
}
__device__ __forceinline__ unsigned cvt_pk(float lo, float hi) {
  unsigned r;
  asm("v_cvt_pk_bf16_f32 %0, %1, %2" : "=v"(r) : "v"(lo), "v"(hi));
  return r;
}
__device__ __forceinline__ float clamp01(float v) {
  return fminf(fmaxf(v, 0.f), 1.f);
}

__device__ __forceinline__ int xat_sw(int node) {
  return ((node & 15) << 3) | ((node & 1) << 2);
}
// read XA_T[t][lane]: all lanes same node t -> 128B XOR'd span, 2 lanes/bank
__device__ __forceinline__ float xat_read(const char* __restrict__ xat, int t, int lane2) {
  unsigned hw = *(const unsigned short*)(xat + t * 128 + (lane2 ^ xat_sw(t)));
  return bfraw(hw);
}

// ---------------- prep: A (f32) + W row -> bf16 MFMA-fragment layout in d_ws ------------
// u32x4 index = ct*512 + ks*64 + lane
// holds A[col = ct*16 + (lane&15)][k = ks*32 + (lane>>4)*8 .. +8)  (col 1023 -> W[0:256))
__global__ void prep_frag(const float* __restrict__ A, const float* __restrict__ W,
                          u32x4* __restrict__ wsf)
{
  int t    = blockIdx.x * 512 + threadIdx.x;      // 0..32767
  int lane = t & 63;
  int ks   = (t >> 6) & 7;
  int ct   = t >> 9;
  int col  = ct * 16 + (lane & 15);
  int k0   = ks * 32 + ((lane >> 4) << 3);
  const float* src = (col < NSPLIT) ? (A + col * DIM + k0) : (W + k0);
  float4_t a0 = *(const float4_t*)src;
  float4_t a1 = *(const float4_t*)(src + 4);
  u32x4 p;
  p[0] = cvt_pk(a0[0], a0[1]);
  p[1] = cvt_pk(a0[2], a0[3]);
  p[2] = cvt_pk(a1[0], a1[1]);
  p[3] = cvt_pk(a1[2], a1[3]);
  wsf[t] = p;
}

// ---------------- B-fragment load (one col-tile, all 8 k-steps) ----------------
template<bool USE_WS>
__device__ __forceinline__ void load_bfr(int ct, bf16x8* dst, int lane,
                                         const u32x4* __restrict__ wsf,
                                         const float* __restrict__ A,
                                         const float* __restrict__ W)
{
  if constexpr (USE_WS) {
    const u32x4* fp = wsf + ct * 512 + lane;
#pragma unroll
    for (int ks = 0; ks < 8; ++ks)
      dst[ks] = __builtin_bit_cast(bf16x8, fp[ks * 64]);
  } else {
    int col = ct * 16 + (lane & 15);
    int k0  = (lane >> 4) << 3;
    const float* ap = (col < NSPLIT) ? (A + col * DIM) : W;
#pragma unroll
    for (int ks = 0; ks < 8; ++ks) {
      float4_t a0 = *(const float4_t*)(ap + ks * 32 + k0);
      float4_t a1 = *(const float4_t*)(ap + ks * 32 + k0 + 4);
      unsigned q0 = ((unsigned)(unsigned short)f2bf(a0[0])) | (((unsigned)(unsigned short)f2bf(a0[1])) << 16);
      unsigned q1 = ((unsigned)(unsigned short)f2bf(a0[2])) | (((unsigned)(unsigned short)f2bf(a0[3])) << 16);
      unsigned q2 = ((unsigned)(unsigned short)f2bf(a1[0])) | (((unsigned)(unsigned short)f2bf(a1[1])) << 16);
      unsigned q3 = ((unsigned)(unsigned short)f2bf(a1[2])) | (((unsigned)(unsigned short)f2bf(a1[3])) << 16);
      u32x4 p = {q0, q1, q2, q3};
      dst[ks] = __builtin_bit_cast(bf16x8, p);
    }
  }
}

// ---------------- transposed tree walk: lane = sample ----------------
// dfs at split node t adds contributions of t's two z-children and recurses.
// All branching is wave-uniform (ballot), so no divergence; q only decreases,
// so a subtree with all-lane q<=0 contributes exactly 0 (clip floor).
template<int D>
__device__ __forceinline__ void dfs(int t, float q, float& acc,
                                    const char* __restrict__ xat, int lane2,
                                    const float* __restrict__ Wz)
{
  if (__ballot(q > 0.f) == 0ull) return;
  float xa = xat_read(xat, t, lane2);
  float qL = fminf(q, xa);          // child 2t+1 (odd, left, +)
  float qR = fminf(q, -xa);         // child 2t+2 (even, right, -)
  acc += clamp01(qL) * Wz[2 * t + 1] + clamp01(qR) * Wz[2 * t + 2];
  if constexpr (D > 1) {
    dfs<D - 1>(2 * t + 1, qL, acc, xat, lane2, Wz);
    dfs<D - 1>(2 * t + 2, qR, acc, xat, lane2, Wz);
  }
}

// ---------------- fused main kernel ----------------
// 1 block/CU (160 KiB LDS), 8 waves = 2/SIMD; register budget pinned to 256.
template<bool USE_WS>
__global__ __launch_bounds__(NTHREADS) __attribute__((amdgpu_waves_per_eu(2, 2)))
void lt_main(const float* __restrict__ X, const float* __restrict__ A,
             const float* __restrict__ W, const float* __restrict__ Bv,
             const u32x4* __restrict__ wsf, float* __restrict__ Out)
{
  const int tid  = threadIdx.x;
  const int lane = tid & 63;
  const int wave = tid >> 6;
  const int m0   = blockIdx.x * BM;

  // ---- issue pass-0 B fragments early (L2 latency overlaps X staging) ----
  bf16x8 b0[8], b1[8];
  load_bfr<USE_WS>(wave, b0, lane, wsf, A, W);

  // ---- stage x tile: contiguous 64*255 f32 region, float4 loads ----
  {
    const float4_t* Xt = (const float4_t*)(X + (size_t)m0 * INSZ);
#pragma unroll
    for (int i = 0; i < 8; ++i) {
      int idx = tid + i * NTHREADS;
      if (idx < 4080) {                      // 64*255/4
        float4_t v = Xt[idx];
#pragma unroll
        for (int e = 0; e < 4; ++e) {
          int g   = idx * 4 + e;
          int row = g / 255;
          int col = g - row * 255;
          *(short*)(smem + (((row << 9) + (col << 1)) ^ ((row & 7) << 4))) = f2bf(v[e]);
        }
      }
    }
    if (tid < BM)                            // bias column (=1.0)
      *(short*)(smem + (((tid << 9) + (255 << 1)) ^ ((tid & 7) << 4))) = (short)0x3f80;
  }
  __syncthreads();

  // ---- preload x fragments: 4 M-tiles x 8 K-steps (128 VGPR) ----
  bf16x8 xf[NMT][8];
#pragma unroll
  for (int mt = 0; mt < NMT; ++mt) {
    int row = mt * 16 + (lane & 15);
#pragma unroll
    for (int ks = 0; ks < 8; ++ks) {
      int kk = ks * 32 + ((lane >> 4) << 3);
      xf[mt][ks] = *(const bf16x8*)(smem + (((row << 9) + (kk << 1)) ^ ((row & 7) << 4)));
    }
  }
  // no barrier: phase 1 writes only the XA_T region, x tile stays intact

  char* xat = smem + XA_OFF;

  // ---- phase 1: 8 passes; wave owns col-tile ct = p*8 + wave ----
#pragma unroll
  for (int p = 0; p < NPASS; ++p) {
    bf16x8* cur = (p & 1) ? b1 : b0;
    bf16x8* nxt = (p & 1) ? b0 : b1;
    if (p < NPASS - 1)
      load_bfr<USE_WS>((p + 1) * 8 + wave, nxt, lane, wsf, A, W);   // prefetch next

    f32x4 acc[NMT];
#pragma unroll
    for (int mt = 0; mt < NMT; ++mt) acc[mt] = f32x4{0.f, 0.f, 0.f, 0.f};
#pragma unroll
    for (int ks = 0; ks < 8; ++ks) {
#pragma unroll
      for (int mt = 0; mt < NMT; ++mt)
        acc[mt] = __builtin_amdgcn_mfma_f32_16x16x32_bf16(xf[mt][ks], cur[ks], acc[mt], 0, 0, 0);
    }

    // write XA_T[node][sample]: node = ct*16 + (lane&15); 2 samples per u32 store
    // (f2bf-based pack -- see NOTE at f2bf about the cvt_pk-on-accumulator hazard)
    int node = (p * 8 + wave) * 16 + (lane & 15);
    int sw   = xat_sw(node);
    char* xrow = xat + node * 128;
#pragma unroll
    for (int mt = 0; mt < NMT; ++mt) {
#pragma unroll
      for (int h = 0; h < 2; ++h) {
        int s0 = mt * 16 + ((lane >> 4) << 2) + h * 2;
        unsigned lo = (unsigned short)f2bf(acc[mt][2 * h]);
        unsigned hi = (unsigned short)f2bf(acc[mt][2 * h + 1]);
        *(unsigned*)(xrow + ((s0 * 2) ^ sw)) = lo | (hi << 16);
      }
    }
  }
  __syncthreads();

  // ---- phase 2: transposed walk, lane = sample ----
  const float* Wz    = W + DIM;
  const int    lane2 = lane << 1;

  int s3 = 7 + wave;                         // this wave's level-3 subtree root
  int a2 = (s3 - 1) >> 1;                    // level-2 ancestor
  int a1 = (a2 - 1) >> 1;                    // level-1 ancestor
  float q = 1.f;
  {
    float x0 = xat_read(xat, 0,  lane2); q = fminf(q, (a1 & 1) ? x0 : -x0);
    float x1 = xat_read(xat, a1, lane2); q = fminf(q, (a2 & 1) ? x1 : -x1);
    float x2 = xat_read(xat, a2, lane2); q = fminf(q, (s3 & 1) ? x2 : -x2);
  }
  float acc = 0.f;
  dfs<7>(s3, q, acc, xat, lane2, Wz);        // z-nodes 15..2046 (this subtree)
  if (wave == 0)
    dfs<3>(0, 1.f, acc, xat, lane2, Wz);     // z-nodes 1..14

  // ---- cross-wave reduction via x-tile region (dead: phase 1 is complete) ----
  float* part = (float*)smem;
  part[(wave << 6) + lane] = acc;
  __syncthreads();

  if (tid < BM) {
    float sum = 0.f;
#pragma unroll
    for (int w = 0; w < 8; ++w) sum += part[(w << 6) + tid];
    float xw = xat_read(xat, 1023, tid << 1);       // x.Wx from MFMA col 1023
    float v  = sum + xw + Bv[0] + Wz[0];            // + b + root weight (z0 = 1)
    Out[m0 + tid] = 1.f / (1.f + __expf(-v));
  }
}

extern "C" void kernel_launch(void* const* d_in, const int* in_sizes, int n_in,
                              void* d_out, int out_size, void* d_ws, size_t ws_size,
                              hipStream_t stream) {
  (void)in_sizes; (void)n_in; (void)out_size;
  const float* X  = (const float*)d_in[0];
  const float* A  = (const float*)d_in[1];
  const float* W  = (const float*)d_in[2];
  const float* Bv = (const float*)d_in[3];
  float* Out = (float*)d_out;

  const bool use_ws = (d_ws != nullptr) && (ws_size >= WS_NEED);
  if (use_ws) {
    prep_frag<<<64, 512, 0, stream>>>(A, W, (u32x4*)d_ws);
    hipFuncSetAttribute(reinterpret_cast<const void*>(lt_main<true>),
                        hipFuncAttributeMaxDynamicSharedMemorySize, LDS_BYTES);
    lt_main<true><<<NSAMP / BM, NTHREADS, LDS_BYTES, stream>>>(
        X, A, W, Bv, (const u32x4*)d_ws, Out);
  } else {
    hipFuncSetAttribute(reinterpret_cast<const void*>(lt_main<false>),
                        hipFuncAttributeMaxDynamicSharedMemorySize, LDS_BYTES);
    lt_main<false><<<NSAMP / BM, NTHREADS, LDS_BYTES, stream>>>(
        X, A, W, Bv, nullptr, Out);
  }
}